// Round 5
// baseline (296.533 us; speedup 1.0000x reference)
//
#include <hip/hip_runtime.h>
#include <math.h>

#define N_PTS 131072
#define BSEG 64
#define CC 256
#define BM 64                    // rows per block (all 4 waves share rows)
#define NSTEP 8                  // K-steps of 32
#define EXP_SHIFT 4.0f

#define INV_SQRT_DH 0.17677669529663687f  // 1/sqrt(32)

typedef short v8s __attribute__((ext_vector_type(8)));
typedef float v4f __attribute__((ext_vector_type(4)));

__device__ __forceinline__ float bf2f(unsigned short h) {
    unsigned u = ((unsigned)h) << 16;
    return __builtin_bit_cast(float, u);
}

// f32 -> bf16 round-to-nearest-even
__device__ __forceinline__ unsigned short f2bf(float f) {
    unsigned u = __builtin_bit_cast(unsigned, f);
    u += 0x7fffu + ((u >> 16) & 1u);
    return (unsigned short)(u >> 16);
}

// split 8 fp32 -> hi/lo bf16 fragment pair (packed)
__device__ __forceinline__ void split8v(const float* x, v8s* hi, v8s* lo) {
    int h2[4], l2[4];
    #pragma unroll
    for (int i = 0; i < 4; ++i) {
        float a = x[2 * i], b = x[2 * i + 1];
        unsigned short ha = f2bf(a), hb = f2bf(b);
        float ra = a - bf2f(ha), rb = b - bf2f(hb);
        unsigned short la = f2bf(ra), lb = f2bf(rb);
        h2[i] = (int)(((unsigned)hb << 16) | ha);
        l2[i] = (int)(((unsigned)lb << 16) | la);
    }
    *hi = __builtin_bit_cast(v8s, make_int4(h2[0], h2[1], h2[2], h2[3]));
    *lo = __builtin_bit_cast(v8s, make_int4(l2[0], l2[1], l2[2], l2[3]));
}

__device__ __forceinline__ v8s as_v8s(int4 v) { return __builtin_bit_cast(v8s, v); }

// ---------------------------------------------------------------------------
// K1: kps = (k @ Wk^T + bk)/sqrt(DH) ; vp = v @ Wv^T + bv ; zero ssum
// ---------------------------------------------------------------------------
__global__ __launch_bounds__(256) void kv_proj_kernel(
    const float* __restrict__ k, const float* __restrict__ v,
    const float* __restrict__ Wk, const float* __restrict__ bk,
    const float* __restrict__ Wv, const float* __restrict__ bv,
    float* __restrict__ kps, float* __restrict__ vp, float* __restrict__ ssum) {
    int b = blockIdx.x;
    int c = threadIdx.x;
    const float4* krow  = (const float4*)(k + (size_t)b * CC);
    const float4* vrow  = (const float4*)(v + (size_t)b * CC);
    const float4* wkrow = (const float4*)(Wk + (size_t)c * CC);
    const float4* wvrow = (const float4*)(Wv + (size_t)c * CC);
    float accK = 0.f, accV = 0.f;
    #pragma unroll 8
    for (int i = 0; i < CC / 4; ++i) {
        float4 kk = krow[i], wk = wkrow[i];
        accK += kk.x * wk.x + kk.y * wk.y + kk.z * wk.z + kk.w * wk.w;
        float4 vv = vrow[i], wv = wvrow[i];
        accV += vv.x * wv.x + vv.y * wv.y + vv.z * wv.z + vv.w * wv.w;
    }
    kps[b * CC + c] = (accK + bk[c]) * INV_SQRT_DH;
    vp[b * CC + c] = accV + bv[c];
    ssum[b * CC + c] = 0.f;
}

// ---------------------------------------------------------------------------
// K1b: split Wq/Wo into hi/lo bf16 planes, layout W2[p][kf(32)][n(256)][8]
// ---------------------------------------------------------------------------
__global__ __launch_bounds__(256) void wsplit_kernel(
    const float* __restrict__ Wq, const float* __restrict__ Wo,
    short* __restrict__ W2q, short* __restrict__ W2o) {
    int bx = blockIdx.x;
    const float* W = (bx >= 32) ? Wo : Wq;
    short* W2 = (bx >= 32) ? W2o : W2q;
    int kf = bx & 31;
    int n = threadIdx.x;
    const float* src = W + (size_t)n * CC + kf * 8;
    float x[8];
    float4 x0 = *(const float4*)(src);
    float4 x1 = *(const float4*)(src + 4);
    x[0]=x0.x; x[1]=x0.y; x[2]=x0.z; x[3]=x0.w;
    x[4]=x1.x; x[5]=x1.y; x[6]=x1.z; x[7]=x1.w;
    v8s hi, lo;
    split8v(x, &hi, &lo);
    *(v8s*)&W2[((size_t)(0 * 32 + kf) * 256 + n) * 8] = hi;
    *(v8s*)&W2[((size_t)(1 * 32 + kf) * 256 + n) * 8] = lo;
}

// ---------------------------------------------------------------------------
// GEMM (bf16x3 MFMA), no LDS, no barriers. BM=64 rows/block, 4 waves, each
// wave owns a 64-col strip (wn). A frags loaded fp32 from global (L1-shared
// across waves), split in-register. B frags from W2 (L2-resident).
//  MODE 0: A=q. Epilogue: p = exp((acc+bq[c])*kps[b,c] - 4) -> attn;
//          fused segment-sum atomicAdd ssum[b,c] += p.
//  MODE 1: A=p, frag transform x = p * SV[b,c]. Epilogue: acc + bo[c] -> out.
// ---------------------------------------------------------------------------
template <int MODE>
__global__ __launch_bounds__(256) void gemm3_kernel(
    const float* __restrict__ A, const short* __restrict__ W2,
    const float* __restrict__ bias, float* __restrict__ Out,
    const int* __restrict__ batch, const float* __restrict__ kps,
    const float* __restrict__ SV, float* __restrict__ ssum) {
    const int tid = threadIdx.x;
    const int lane = tid & 63;
    const int wn = tid >> 6;        // 0..3: 64-col strip
    const int kfl = lane >> 4;      // k-chunk 0..3
    const int rl = lane & 15;       // row (A-frag) / col (B-frag) within frag
    const int m0 = blockIdx.x * BM;

    // per-lane segment ids for the 4 A-frag rows (MODE 1 transform)
    int abseg[4];
    if (MODE == 1) {
        #pragma unroll
        for (int mi = 0; mi < 4; ++mi) abseg[mi] = batch[m0 + mi * 16 + rl];
    }

    v4f acc[4][4];
    #pragma unroll
    for (int i = 0; i < 4; ++i)
        #pragma unroll
        for (int j = 0; j < 4; ++j) acc[i][j] = (v4f){0.f, 0.f, 0.f, 0.f};

    #pragma unroll 2
    for (int s = 0; s < NSTEP; ++s) {
        // B fragments (hi/lo planes), straight from L2-resident W2
        v8s bfr[2][4];
        #pragma unroll
        for (int p = 0; p < 2; ++p)
            #pragma unroll
            for (int ni = 0; ni < 4; ++ni)
                bfr[p][ni] = as_v8s(*(const int4*)(W2 +
                    ((size_t)(p * 32 + s * 4 + kfl) * 256 + wn * 64 + ni * 16 + rl) * 8));

        #pragma unroll
        for (int mi = 0; mi < 4; ++mi) {
            // A fragment: 8 fp32 straight from global (L1 shares across waves)
            int row = m0 + mi * 16 + rl;
            const float4* ap = (const float4*)(A + (size_t)row * CC + s * 32 + kfl * 8);
            float4 x0 = ap[0];
            float4 x1 = ap[1];
            float x[8];
            x[0]=x0.x; x[1]=x0.y; x[2]=x0.z; x[3]=x0.w;
            x[4]=x1.x; x[5]=x1.y; x[6]=x1.z; x[7]=x1.w;
            if (MODE == 1) {
                const float4* sp = (const float4*)(SV + (size_t)abseg[mi] * CC + s * 32 + kfl * 8);
                float4 s0 = sp[0];
                float4 s1 = sp[1];
                x[0] *= s0.x; x[1] *= s0.y; x[2] *= s0.z; x[3] *= s0.w;
                x[4] *= s1.x; x[5] *= s1.y; x[6] *= s1.z; x[7] *= s1.w;
            }
            v8s ah, al;
            split8v(x, &ah, &al);
            #pragma unroll
            for (int ni = 0; ni < 4; ++ni) {
                acc[mi][ni] = __builtin_amdgcn_mfma_f32_16x16x32_bf16(
                    al, bfr[0][ni], acc[mi][ni], 0, 0, 0);   // lo*hi
                acc[mi][ni] = __builtin_amdgcn_mfma_f32_16x16x32_bf16(
                    ah, bfr[1][ni], acc[mi][ni], 0, 0, 0);   // hi*lo
                acc[mi][ni] = __builtin_amdgcn_mfma_f32_16x16x32_bf16(
                    ah, bfr[0][ni], acc[mi][ni], 0, 0, 0);   // hi*hi
            }
        }
    }

    const int colb = wn * 64 + rl;

    if (MODE == 0) {
        int bfirst = batch[m0];
        int blast = batch[m0 + BM - 1];
        if (bfirst == blast) {
            // fast path: whole block in one segment
            int b = bfirst;
            float bb[4], kk[4], csum[4];
            #pragma unroll
            for (int ni = 0; ni < 4; ++ni) {
                int col = colb + ni * 16;
                bb[ni] = bias[col];
                kk[ni] = kps[(size_t)b * CC + col];
                csum[ni] = 0.f;
            }
            #pragma unroll
            for (int mi = 0; mi < 4; ++mi)
                #pragma unroll
                for (int r4 = 0; r4 < 4; ++r4) {
                    int row = m0 + mi * 16 + kfl * 4 + r4;
                    #pragma unroll
                    for (int ni = 0; ni < 4; ++ni) {
                        float p = __expf((acc[mi][ni][r4] + bb[ni]) * kk[ni] - EXP_SHIFT);
                        Out[(size_t)row * CC + colb + ni * 16] = p;
                        csum[ni] += p;
                    }
                }
            #pragma unroll
            for (int ni = 0; ni < 4; ++ni) {
                float vsum = csum[ni];
                vsum += __shfl_xor(vsum, 16);
                vsum += __shfl_xor(vsum, 32);
                if (kfl == 0) atomicAdd(&ssum[(size_t)b * CC + colb + ni * 16], vsum);
            }
        } else {
            // slow path: segment boundary inside block (rare)
            int curb = -1;
            float racc[4] = {0.f, 0.f, 0.f, 0.f};
            #pragma unroll
            for (int mi = 0; mi < 4; ++mi)
                #pragma unroll
                for (int r4 = 0; r4 < 4; ++r4) {
                    int row = m0 + mi * 16 + kfl * 4 + r4;
                    int b = batch[row];
                    if (b != curb) {
                        if (curb >= 0) {
                            #pragma unroll
                            for (int ni = 0; ni < 4; ++ni) {
                                atomicAdd(&ssum[(size_t)curb * CC + colb + ni * 16], racc[ni]);
                                racc[ni] = 0.f;
                            }
                        }
                        curb = b;
                    }
                    #pragma unroll
                    for (int ni = 0; ni < 4; ++ni) {
                        int col = colb + ni * 16;
                        float p = __expf((acc[mi][ni][r4] + bias[col]) *
                                         kps[(size_t)b * CC + col] - EXP_SHIFT);
                        Out[(size_t)row * CC + col] = p;
                        racc[ni] += p;
                    }
                }
            #pragma unroll
            for (int ni = 0; ni < 4; ++ni)
                atomicAdd(&ssum[(size_t)curb * CC + colb + ni * 16], racc[ni]);
        }
    } else {
        #pragma unroll
        for (int mi = 0; mi < 4; ++mi)
            #pragma unroll
            for (int r4 = 0; r4 < 4; ++r4) {
                int row = m0 + mi * 16 + kfl * 4 + r4;
                #pragma unroll
                for (int ni = 0; ni < 4; ++ni) {
                    int col = colb + ni * 16;
                    Out[(size_t)row * CC + col] = acc[mi][ni][r4] + bias[col];
                }
            }
    }
}

// ---------------------------------------------------------------------------
// K_sv: SV[b,c] = vp[b,c] / ssum[b,c]
// ---------------------------------------------------------------------------
__global__ __launch_bounds__(256) void sv_kernel(
    const float* __restrict__ vp, const float* __restrict__ ssum,
    float* __restrict__ SV) {
    int i = blockIdx.x * 256 + threadIdx.x;
    SV[i] = vp[i] / ssum[i];
}

// ---------------------------------------------------------------------------
extern "C" void kernel_launch(void* const* d_in, const int* in_sizes, int n_in,
                              void* d_out, int out_size, void* d_ws, size_t ws_size,
                              hipStream_t stream) {
    const float* q  = (const float*)d_in[0];
    const float* k  = (const float*)d_in[1];
    const float* v  = (const float*)d_in[2];
    const int* batch = (const int*)d_in[3];
    const float* Wq = (const float*)d_in[4];
    const float* bq = (const float*)d_in[5];
    const float* Wk = (const float*)d_in[6];
    const float* bk = (const float*)d_in[7];
    const float* Wv = (const float*)d_in[8];
    const float* bv = (const float*)d_in[9];
    const float* Wo = (const float*)d_in[10];
    const float* bo = (const float*)d_in[11];
    float* out = (float*)d_out;

    char* wsp = (char*)d_ws;
    float* attn = (float*)wsp;  wsp += (size_t)N_PTS * CC * sizeof(float);       // 134 MB
    float* kps  = (float*)wsp;  wsp += (size_t)BSEG * CC * sizeof(float);
    float* vp   = (float*)wsp;  wsp += (size_t)BSEG * CC * sizeof(float);
    float* SVb  = (float*)wsp;  wsp += (size_t)BSEG * CC * sizeof(float);
    float* ssum = (float*)wsp;  wsp += (size_t)BSEG * CC * sizeof(float);
    short* W2q  = (short*)wsp;  wsp += (size_t)2 * 32 * 256 * 8 * sizeof(short); // 256 KB
    short* W2o  = (short*)wsp;  wsp += (size_t)2 * 32 * 256 * 8 * sizeof(short);

    kv_proj_kernel<<<BSEG, 256, 0, stream>>>(k, v, Wk, bk, Wv, bv, kps, vp, ssum);
    wsplit_kernel<<<64, 256, 0, stream>>>(Wq, Wo, W2q, W2o);

    gemm3_kernel<0><<<N_PTS / BM, 256, 0, stream>>>(
        q, W2q, bq, attn, batch, kps, nullptr, ssum);

    sv_kernel<<<BSEG, 256, 0, stream>>>(vp, ssum, SVb);

    gemm3_kernel<1><<<N_PTS / BM, 256, 0, stream>>>(
        attn, W2o, bo, out, batch, nullptr, SVb, nullptr);
}

// Round 6
// 231.280 us; speedup vs baseline: 1.2821x; 1.2821x over previous
//
#include <hip/hip_runtime.h>
#include <math.h>

#define N_PTS 131072
#define BSEG 64
#define CC 256
#define BM 32                    // rows per block; A tile fully LDS-resident
#define NSTEP 8                  // K-steps of 32
#define EXP_SHIFT 4.0f
#define PLANE 16384              // bytes per LDS plane: 32 rows * 512B

#define INV_SQRT_DH 0.17677669529663687f  // 1/sqrt(32)

typedef short v8s __attribute__((ext_vector_type(8)));
typedef float v4f __attribute__((ext_vector_type(4)));

__device__ __forceinline__ float bf2f(unsigned short h) {
    unsigned u = ((unsigned)h) << 16;
    return __builtin_bit_cast(float, u);
}

// f32 -> bf16 round-to-nearest-even
__device__ __forceinline__ unsigned short f2bf(float f) {
    unsigned u = __builtin_bit_cast(unsigned, f);
    u += 0x7fffu + ((u >> 16) & 1u);
    return (unsigned short)(u >> 16);
}

// split 8 fp32 -> hi/lo bf16 fragment pair (packed)
__device__ __forceinline__ void split8v(const float* x, v8s* hi, v8s* lo) {
    int h2[4], l2[4];
    #pragma unroll
    for (int i = 0; i < 4; ++i) {
        float a = x[2 * i], b = x[2 * i + 1];
        unsigned short ha = f2bf(a), hb = f2bf(b);
        float ra = a - bf2f(ha), rb = b - bf2f(hb);
        unsigned short la = f2bf(ra), lb = f2bf(rb);
        h2[i] = (int)(((unsigned)hb << 16) | ha);
        l2[i] = (int)(((unsigned)lb << 16) | la);
    }
    *hi = __builtin_bit_cast(v8s, make_int4(h2[0], h2[1], h2[2], h2[3]));
    *lo = __builtin_bit_cast(v8s, make_int4(l2[0], l2[1], l2[2], l2[3]));
}

__device__ __forceinline__ v8s as_v8s(int4 v) { return __builtin_bit_cast(v8s, v); }

// ---------------------------------------------------------------------------
// K1: kps = (k @ Wk^T + bk)/sqrt(DH) ; vp = v @ Wv^T + bv ; zero ssum
// ---------------------------------------------------------------------------
__global__ __launch_bounds__(256) void kv_proj_kernel(
    const float* __restrict__ k, const float* __restrict__ v,
    const float* __restrict__ Wk, const float* __restrict__ bk,
    const float* __restrict__ Wv, const float* __restrict__ bv,
    float* __restrict__ kps, float* __restrict__ vp, float* __restrict__ ssum) {
    int b = blockIdx.x;
    int c = threadIdx.x;
    const float4* krow  = (const float4*)(k + (size_t)b * CC);
    const float4* vrow  = (const float4*)(v + (size_t)b * CC);
    const float4* wkrow = (const float4*)(Wk + (size_t)c * CC);
    const float4* wvrow = (const float4*)(Wv + (size_t)c * CC);
    float accK = 0.f, accV = 0.f;
    #pragma unroll 8
    for (int i = 0; i < CC / 4; ++i) {
        float4 kk = krow[i], wk = wkrow[i];
        accK += kk.x * wk.x + kk.y * wk.y + kk.z * wk.z + kk.w * wk.w;
        float4 vv = vrow[i], wv = wvrow[i];
        accV += vv.x * wv.x + vv.y * wv.y + vv.z * wv.z + vv.w * wv.w;
    }
    kps[b * CC + c] = (accK + bk[c]) * INV_SQRT_DH;
    vp[b * CC + c] = accV + bv[c];
    ssum[b * CC + c] = 0.f;
}

// ---------------------------------------------------------------------------
// K1b: split Wq/Wo into hi/lo bf16 planes, layout W2[p][kf(32)][n(256)][8]
// ---------------------------------------------------------------------------
__global__ __launch_bounds__(256) void wsplit_kernel(
    const float* __restrict__ Wq, const float* __restrict__ Wo,
    short* __restrict__ W2q, short* __restrict__ W2o) {
    int bx = blockIdx.x;
    const float* W = (bx >= 32) ? Wo : Wq;
    short* W2 = (bx >= 32) ? W2o : W2q;
    int kf = bx & 31;
    int n = threadIdx.x;
    const float* src = W + (size_t)n * CC + kf * 8;
    float x[8];
    float4 x0 = *(const float4*)(src);
    float4 x1 = *(const float4*)(src + 4);
    x[0]=x0.x; x[1]=x0.y; x[2]=x0.z; x[3]=x0.w;
    x[4]=x1.x; x[5]=x1.y; x[6]=x1.z; x[7]=x1.w;
    v8s hi, lo;
    split8v(x, &hi, &lo);
    *(v8s*)&W2[((size_t)(0 * 32 + kf) * 256 + n) * 8] = hi;
    *(v8s*)&W2[((size_t)(1 * 32 + kf) * 256 + n) * 8] = lo;
}

// ---------------------------------------------------------------------------
// GEMM (bf16x3 MFMA): A tile (32 rows x full K=256, hi+lo) staged in LDS ONCE
// (swizzled, conflict-free), ONE barrier, then 8 K-steps of pure
// {B-from-L2 + ds_read + MFMA} with no further synchronization.
//  MODE 0: A=q. Epilogue: p = exp((acc+bq[c])*kps[b,c] - 4) -> attn;
//          fused segment-sum atomicAdd ssum[b,c] += p.
//  MODE 1: A=p, staged transform x = p * SV[b,c]. Epilogue: acc + bo[c].
// ---------------------------------------------------------------------------
template <int MODE>
__global__ __launch_bounds__(256, 4) void gemm3_kernel(
    const float* __restrict__ A, const short* __restrict__ W2,
    const float* __restrict__ bias, float* __restrict__ Out,
    const int* __restrict__ batch, const float* __restrict__ kps,
    const float* __restrict__ SV, float* __restrict__ ssum) {
    __shared__ char ldsb[2 * PLANE];   // 32 KB: [plane][row 32][chunk16 32]

    const int tid = threadIdx.x;
    const int lane = tid & 63;
    const int wn = tid >> 6;        // 0..3: 64-col strip per wave
    const int kfl = lane >> 4;      // k-chunk 0..3 within a 32-k step
    const int rl = lane & 15;       // row (A) / col (B) within fragment
    const int m0 = blockIdx.x * BM;

    // ---- stage A tile: fp32 -> split bf16 hi/lo, swizzled LDS ----
    #pragma unroll
    for (int i = 0; i < 4; ++i) {
        int j = i * 256 + tid;          // 0..1023
        int row = j >> 5;               // 0..31
        int ch = j & 31;                // 16B chunk (8 cols)
        const float4* ap = (const float4*)(A + (size_t)(m0 + row) * CC + ch * 8);
        float4 x0 = ap[0];
        float4 x1 = ap[1];
        float x[8];
        x[0]=x0.x; x[1]=x0.y; x[2]=x0.z; x[3]=x0.w;
        x[4]=x1.x; x[5]=x1.y; x[6]=x1.z; x[7]=x1.w;
        if (MODE == 1) {
            int b = batch[m0 + row];
            const float4* sp = (const float4*)(SV + (size_t)b * CC + ch * 8);
            float4 s0 = sp[0];
            float4 s1 = sp[1];
            x[0] *= s0.x; x[1] *= s0.y; x[2] *= s0.z; x[3] *= s0.w;
            x[4] *= s1.x; x[5] *= s1.y; x[6] *= s1.z; x[7] *= s1.w;
        }
        v8s hi, lo;
        split8v(x, &hi, &lo);
        int off = row * 512 + ((ch ^ (row & 7)) * 16);
        *(v8s*)(ldsb + off) = hi;
        *(v8s*)(ldsb + PLANE + off) = lo;
    }

    v4f acc[2][4];
    #pragma unroll
    for (int i = 0; i < 2; ++i)
        #pragma unroll
        for (int j = 0; j < 4; ++j) acc[i][j] = (v4f){0.f, 0.f, 0.f, 0.f};

    // prefetch B for s=0 (before the barrier; independent of LDS)
    v8s bfr[2][4];
    #pragma unroll
    for (int p = 0; p < 2; ++p)
        #pragma unroll
        for (int ni = 0; ni < 4; ++ni)
            bfr[p][ni] = as_v8s(*(const int4*)(W2 +
                ((size_t)(p * 32 + kfl) * 256 + wn * 64 + ni * 16 + rl) * 8));

    __syncthreads();   // the ONLY barrier

    #pragma unroll 2
    for (int s = 0; s < NSTEP; ++s) {
        v8s bnext[2][4];
        if (s + 1 < NSTEP) {
            #pragma unroll
            for (int p = 0; p < 2; ++p)
                #pragma unroll
                for (int ni = 0; ni < 4; ++ni)
                    bnext[p][ni] = as_v8s(*(const int4*)(W2 +
                        ((size_t)(p * 32 + (s + 1) * 4 + kfl) * 256 + wn * 64 + ni * 16 + rl) * 8));
        }
        #pragma unroll
        for (int mi = 0; mi < 2; ++mi) {
            int abase = (mi * 16 + rl) * 512 + (((s * 4 + kfl) ^ (rl & 7)) * 16);
            v8s ah = *(const v8s*)(ldsb + abase);
            v8s al = *(const v8s*)(ldsb + PLANE + abase);
            #pragma unroll
            for (int ni = 0; ni < 4; ++ni) {
                acc[mi][ni] = __builtin_amdgcn_mfma_f32_16x16x32_bf16(
                    al, bfr[0][ni], acc[mi][ni], 0, 0, 0);   // lo*hi
                acc[mi][ni] = __builtin_amdgcn_mfma_f32_16x16x32_bf16(
                    ah, bfr[1][ni], acc[mi][ni], 0, 0, 0);   // hi*lo
                acc[mi][ni] = __builtin_amdgcn_mfma_f32_16x16x32_bf16(
                    ah, bfr[0][ni], acc[mi][ni], 0, 0, 0);   // hi*hi
            }
        }
        #pragma unroll
        for (int p = 0; p < 2; ++p)
            #pragma unroll
            for (int ni = 0; ni < 4; ++ni) bfr[p][ni] = bnext[p][ni];
    }

    const int colb = wn * 64 + rl;

    if (MODE == 0) {
        int bfirst = batch[m0];
        int blast = batch[m0 + BM - 1];
        if (bfirst == blast) {
            // fast path: whole block in one segment
            int b = bfirst;
            float bb[4], kk[4], csum[4];
            #pragma unroll
            for (int ni = 0; ni < 4; ++ni) {
                int col = colb + ni * 16;
                bb[ni] = bias[col];
                kk[ni] = kps[(size_t)b * CC + col];
                csum[ni] = 0.f;
            }
            #pragma unroll
            for (int mi = 0; mi < 2; ++mi)
                #pragma unroll
                for (int r4 = 0; r4 < 4; ++r4) {
                    int row = m0 + mi * 16 + kfl * 4 + r4;
                    #pragma unroll
                    for (int ni = 0; ni < 4; ++ni) {
                        float p = __expf((acc[mi][ni][r4] + bb[ni]) * kk[ni] - EXP_SHIFT);
                        Out[(size_t)row * CC + colb + ni * 16] = p;
                        csum[ni] += p;
                    }
                }
            #pragma unroll
            for (int ni = 0; ni < 4; ++ni) {
                float vsum = csum[ni];
                vsum += __shfl_xor(vsum, 16);
                vsum += __shfl_xor(vsum, 32);
                if (kfl == 0) atomicAdd(&ssum[(size_t)b * CC + colb + ni * 16], vsum);
            }
        } else {
            // slow path: segment boundary inside block (rare)
            int curb = -1;
            float racc[4] = {0.f, 0.f, 0.f, 0.f};
            #pragma unroll
            for (int mi = 0; mi < 2; ++mi)
                #pragma unroll
                for (int r4 = 0; r4 < 4; ++r4) {
                    int row = m0 + mi * 16 + kfl * 4 + r4;
                    int b = batch[row];
                    if (b != curb) {
                        if (curb >= 0) {
                            #pragma unroll
                            for (int ni = 0; ni < 4; ++ni) {
                                atomicAdd(&ssum[(size_t)curb * CC + colb + ni * 16], racc[ni]);
                                racc[ni] = 0.f;
                            }
                        }
                        curb = b;
                    }
                    #pragma unroll
                    for (int ni = 0; ni < 4; ++ni) {
                        int col = colb + ni * 16;
                        float p = __expf((acc[mi][ni][r4] + bias[col]) *
                                         kps[(size_t)b * CC + col] - EXP_SHIFT);
                        Out[(size_t)row * CC + col] = p;
                        racc[ni] += p;
                    }
                }
            #pragma unroll
            for (int ni = 0; ni < 4; ++ni)
                atomicAdd(&ssum[(size_t)curb * CC + colb + ni * 16], racc[ni]);
        }
    } else {
        #pragma unroll
        for (int mi = 0; mi < 2; ++mi)
            #pragma unroll
            for (int r4 = 0; r4 < 4; ++r4) {
                int row = m0 + mi * 16 + kfl * 4 + r4;
                #pragma unroll
                for (int ni = 0; ni < 4; ++ni) {
                    int col = colb + ni * 16;
                    Out[(size_t)row * CC + col] = acc[mi][ni][r4] + bias[col];
                }
            }
    }
}

// ---------------------------------------------------------------------------
// K_sv: SV[b,c] = vp[b,c] / ssum[b,c]
// ---------------------------------------------------------------------------
__global__ __launch_bounds__(256) void sv_kernel(
    const float* __restrict__ vp, const float* __restrict__ ssum,
    float* __restrict__ SV) {
    int i = blockIdx.x * 256 + threadIdx.x;
    SV[i] = vp[i] / ssum[i];
}

// ---------------------------------------------------------------------------
extern "C" void kernel_launch(void* const* d_in, const int* in_sizes, int n_in,
                              void* d_out, int out_size, void* d_ws, size_t ws_size,
                              hipStream_t stream) {
    const float* q  = (const float*)d_in[0];
    const float* k  = (const float*)d_in[1];
    const float* v  = (const float*)d_in[2];
    const int* batch = (const int*)d_in[3];
    const float* Wq = (const float*)d_in[4];
    const float* bq = (const float*)d_in[5];
    const float* Wk = (const float*)d_in[6];
    const float* bk = (const float*)d_in[7];
    const float* Wv = (const float*)d_in[8];
    const float* bv = (const float*)d_in[9];
    const float* Wo = (const float*)d_in[10];
    const float* bo = (const float*)d_in[11];
    float* out = (float*)d_out;

    char* wsp = (char*)d_ws;
    float* attn = (float*)wsp;  wsp += (size_t)N_PTS * CC * sizeof(float);       // 134 MB
    float* kps  = (float*)wsp;  wsp += (size_t)BSEG * CC * sizeof(float);
    float* vp   = (float*)wsp;  wsp += (size_t)BSEG * CC * sizeof(float);
    float* SVb  = (float*)wsp;  wsp += (size_t)BSEG * CC * sizeof(float);
    float* ssum = (float*)wsp;  wsp += (size_t)BSEG * CC * sizeof(float);
    short* W2q  = (short*)wsp;  wsp += (size_t)2 * 32 * 256 * 8 * sizeof(short); // 256 KB
    short* W2o  = (short*)wsp;  wsp += (size_t)2 * 32 * 256 * 8 * sizeof(short);

    kv_proj_kernel<<<BSEG, 256, 0, stream>>>(k, v, Wk, bk, Wv, bv, kps, vp, ssum);
    wsplit_kernel<<<64, 256, 0, stream>>>(Wq, Wo, W2q, W2o);

    gemm3_kernel<0><<<N_PTS / BM, 256, 0, stream>>>(
        q, W2q, bq, attn, batch, kps, nullptr, ssum);

    sv_kernel<<<BSEG, 256, 0, stream>>>(vp, ssum, SVb);

    gemm3_kernel<1><<<N_PTS / BM, 256, 0, stream>>>(
        attn, W2o, bo, out, batch, nullptr, SVb, nullptr);
}

// Round 8
// 199.524 us; speedup vs baseline: 1.4862x; 1.1592x over previous
//
#include <hip/hip_runtime.h>
#include <math.h>

#define N_PTS 131072
#define BSEG 64
#define CC 256
#define BM 32                    // rows per block; A tile fully LDS-resident
#define NSTEP 8                  // K-steps of 32
#define EXP_SHIFT 4.0f
#define PLANE 16384              // bytes per LDS plane: 32 rows * 512B
#define EPW 40                   // epilogue bounce row stride (floats)

#define INV_SQRT_DH 0.17677669529663687f  // 1/sqrt(32)

typedef short v8s __attribute__((ext_vector_type(8)));
typedef float v4f __attribute__((ext_vector_type(4)));

__device__ __forceinline__ float bf2f(unsigned short h) {
    unsigned u = ((unsigned)h) << 16;
    return __builtin_bit_cast(float, u);
}

// f32 -> bf16 round-to-nearest-even
__device__ __forceinline__ unsigned short f2bf(float f) {
    unsigned u = __builtin_bit_cast(unsigned, f);
    u += 0x7fffu + ((u >> 16) & 1u);
    return (unsigned short)(u >> 16);
}

// split 8 fp32 -> hi/lo bf16 fragment pair (packed)
__device__ __forceinline__ void split8v(const float* x, v8s* hi, v8s* lo) {
    int h2[4], l2[4];
    #pragma unroll
    for (int i = 0; i < 4; ++i) {
        float a = x[2 * i], b = x[2 * i + 1];
        unsigned short ha = f2bf(a), hb = f2bf(b);
        float ra = a - bf2f(ha), rb = b - bf2f(hb);
        unsigned short la = f2bf(ra), lb = f2bf(rb);
        h2[i] = (int)(((unsigned)hb << 16) | ha);
        l2[i] = (int)(((unsigned)lb << 16) | la);
    }
    *hi = __builtin_bit_cast(v8s, make_int4(h2[0], h2[1], h2[2], h2[3]));
    *lo = __builtin_bit_cast(v8s, make_int4(l2[0], l2[1], l2[2], l2[3]));
}

__device__ __forceinline__ v8s as_v8s(int4 v) { return __builtin_bit_cast(v8s, v); }

// ---------------------------------------------------------------------------
// K1: kps = (k @ Wk^T + bk)/sqrt(DH) ; vp = v @ Wv^T + bv ; zero ssum
// ---------------------------------------------------------------------------
__global__ __launch_bounds__(256) void kv_proj_kernel(
    const float* __restrict__ k, const float* __restrict__ v,
    const float* __restrict__ Wk, const float* __restrict__ bk,
    const float* __restrict__ Wv, const float* __restrict__ bv,
    float* __restrict__ kps, float* __restrict__ vp, float* __restrict__ ssum) {
    int b = blockIdx.x;
    int c = threadIdx.x;
    const float4* krow  = (const float4*)(k + (size_t)b * CC);
    const float4* vrow  = (const float4*)(v + (size_t)b * CC);
    const float4* wkrow = (const float4*)(Wk + (size_t)c * CC);
    const float4* wvrow = (const float4*)(Wv + (size_t)c * CC);
    float accK = 0.f, accV = 0.f;
    #pragma unroll 8
    for (int i = 0; i < CC / 4; ++i) {
        float4 kk = krow[i], wk = wkrow[i];
        accK += kk.x * wk.x + kk.y * wk.y + kk.z * wk.z + kk.w * wk.w;
        float4 vv = vrow[i], wv = wvrow[i];
        accV += vv.x * wv.x + vv.y * wv.y + vv.z * wv.z + vv.w * wv.w;
    }
    kps[b * CC + c] = (accK + bk[c]) * INV_SQRT_DH;
    vp[b * CC + c] = accV + bv[c];
    ssum[b * CC + c] = 0.f;
}

// ---------------------------------------------------------------------------
// K1b: split Wq/Wo into hi/lo bf16 planes, layout W2[p][kf(32)][n(256)][8]
// ---------------------------------------------------------------------------
__global__ __launch_bounds__(256) void wsplit_kernel(
    const float* __restrict__ Wq, const float* __restrict__ Wo,
    short* __restrict__ W2q, short* __restrict__ W2o) {
    int bx = blockIdx.x;
    const float* W = (bx >= 32) ? Wo : Wq;
    short* W2 = (bx >= 32) ? W2o : W2q;
    int kf = bx & 31;
    int n = threadIdx.x;
    const float* src = W + (size_t)n * CC + kf * 8;
    float x[8];
    float4 x0 = *(const float4*)(src);
    float4 x1 = *(const float4*)(src + 4);
    x[0]=x0.x; x[1]=x0.y; x[2]=x0.z; x[3]=x0.w;
    x[4]=x1.x; x[5]=x1.y; x[6]=x1.z; x[7]=x1.w;
    v8s hi, lo;
    split8v(x, &hi, &lo);
    *(v8s*)&W2[((size_t)(0 * 32 + kf) * 256 + n) * 8] = hi;
    *(v8s*)&W2[((size_t)(1 * 32 + kf) * 256 + n) * 8] = lo;
}

// ---------------------------------------------------------------------------
// GEMM (bf16x3 MFMA): 512 thr / 8 waves, BM=32 x BN=256, wave owns 32 cols.
// A tile (32 rows x K=256, hi+lo) staged in LDS once; one barrier; 8 K-steps
// of {B-prefetch-from-L2 + ds_read + MFMA}; barrier; LDS-bounce epilogue with
// coalesced nontemporal v4f stores. Streams (A in, Out) are nontemporal so
// W2/kps/SV stay L2-resident.
//  MODE 0: A=q. p = exp((acc+bq[c])*kps[b,c]-4) -> attn; colsum -> ssum atomics.
//  MODE 1: A=p, staged transform x = p * SV[b,c]. Out: acc + bo[c].
// ---------------------------------------------------------------------------
template <int MODE>
__global__ __launch_bounds__(512, 4) void gemm3_kernel(
    const float* __restrict__ A, const short* __restrict__ W2,
    const float* __restrict__ bias, float* __restrict__ Out,
    const int* __restrict__ batch, const float* __restrict__ kps,
    const float* __restrict__ SV, float* __restrict__ ssum) {
    __shared__ char ldsb[2 * PLANE];   // 32 KB

    const int tid = threadIdx.x;
    const int lane = tid & 63;
    const int wn = tid >> 6;        // 0..7: 32-col strip per wave
    const int kfl = lane >> 4;      // k-chunk 0..3 within a 32-k step
    const int rl = lane & 15;       // row (A) / col (B) within fragment
    const int m0 = blockIdx.x * BM;
    const int colb = wn * 32;

    // ---- stage A tile: fp32 -> split bf16 hi/lo, swizzled LDS ----
    #pragma unroll
    for (int i = 0; i < 2; ++i) {
        int j = i * 512 + tid;          // 0..1023
        int row = j >> 5;               // 0..31
        int ch = j & 31;                // 16B chunk (8 cols)
        const v4f* ap = (const v4f*)(A + (size_t)(m0 + row) * CC + ch * 8);
        v4f x0 = __builtin_nontemporal_load(ap);
        v4f x1 = __builtin_nontemporal_load(ap + 1);
        float x[8];
        x[0]=x0.x; x[1]=x0.y; x[2]=x0.z; x[3]=x0.w;
        x[4]=x1.x; x[5]=x1.y; x[6]=x1.z; x[7]=x1.w;
        if (MODE == 1) {
            int b = batch[m0 + row];
            const float4* sp = (const float4*)(SV + (size_t)b * CC + ch * 8);
            float4 s0 = sp[0];
            float4 s1 = sp[1];
            x[0] *= s0.x; x[1] *= s0.y; x[2] *= s0.z; x[3] *= s0.w;
            x[4] *= s1.x; x[5] *= s1.y; x[6] *= s1.z; x[7] *= s1.w;
        }
        v8s hi, lo;
        split8v(x, &hi, &lo);
        int off = row * 512 + ((ch ^ (row & 7)) * 16);
        *(v8s*)(ldsb + off) = hi;
        *(v8s*)(ldsb + PLANE + off) = lo;
    }

    v4f acc[2][2];
    #pragma unroll
    for (int i = 0; i < 2; ++i)
        #pragma unroll
        for (int j = 0; j < 2; ++j) acc[i][j] = (v4f){0.f, 0.f, 0.f, 0.f};

    // prefetch B for s=0 (independent of LDS)
    v8s bcur[2][2];
    #pragma unroll
    for (int p = 0; p < 2; ++p)
        #pragma unroll
        for (int ni = 0; ni < 2; ++ni)
            bcur[p][ni] = as_v8s(*(const int4*)(W2 +
                ((size_t)(p * 32 + kfl) * 256 + colb + ni * 16 + rl) * 8));

    __syncthreads();

    #pragma unroll
    for (int s = 0; s < NSTEP; ++s) {
        v8s bnx[2][2];
        if (s + 1 < NSTEP) {
            #pragma unroll
            for (int p = 0; p < 2; ++p)
                #pragma unroll
                for (int ni = 0; ni < 2; ++ni)
                    bnx[p][ni] = as_v8s(*(const int4*)(W2 +
                        ((size_t)(p * 32 + (s + 1) * 4 + kfl) * 256 + colb + ni * 16 + rl) * 8));
        }
        #pragma unroll
        for (int mi = 0; mi < 2; ++mi) {
            int abase = (mi * 16 + rl) * 512 + (((s * 4 + kfl) ^ (rl & 7)) * 16);
            v8s ah = *(const v8s*)(ldsb + abase);
            v8s al = *(const v8s*)(ldsb + PLANE + abase);
            #pragma unroll
            for (int ni = 0; ni < 2; ++ni) {
                acc[mi][ni] = __builtin_amdgcn_mfma_f32_16x16x32_bf16(
                    al, bcur[0][ni], acc[mi][ni], 0, 0, 0);   // lo*hi
                acc[mi][ni] = __builtin_amdgcn_mfma_f32_16x16x32_bf16(
                    ah, bcur[1][ni], acc[mi][ni], 0, 0, 0);   // hi*lo
                acc[mi][ni] = __builtin_amdgcn_mfma_f32_16x16x32_bf16(
                    ah, bcur[0][ni], acc[mi][ni], 0, 0, 0);   // hi*hi
            }
        }
        #pragma unroll
        for (int p = 0; p < 2; ++p)
            #pragma unroll
            for (int ni = 0; ni < 2; ++ni) bcur[p][ni] = bnx[p][ni];
    }

    __syncthreads();   // A-LDS dead; reuse for epilogue bounce

    // per-wave bounce region: 16 rows x EPW floats
    float* lw = (float*)ldsb + wn * (16 * EPW);
    const int c8 = lane & 7;        // col quad in strip
    const int r8 = lane >> 3;       // row-in-8 for readback

    int bfirst = batch[m0];
    int blast = batch[m0 + BM - 1];

    if (MODE == 0 && bfirst != blast) {
        // slow path: segment boundary inside block (rare; ~63/4096 blocks)
        int curb = -1;
        float racc[2] = {0.f, 0.f};
        #pragma unroll
        for (int mi = 0; mi < 2; ++mi)
            #pragma unroll
            for (int r4 = 0; r4 < 4; ++r4) {
                int row = m0 + mi * 16 + kfl * 4 + r4;
                int b = batch[row];
                if (b != curb) {
                    if (curb >= 0) {
                        #pragma unroll
                        for (int ni = 0; ni < 2; ++ni) {
                            atomicAdd(&ssum[(size_t)curb * CC + colb + ni * 16 + rl], racc[ni]);
                            racc[ni] = 0.f;
                        }
                    }
                    curb = b;
                }
                #pragma unroll
                for (int ni = 0; ni < 2; ++ni) {
                    int col = colb + ni * 16 + rl;
                    float p = __expf((acc[mi][ni][r4] + bias[col]) *
                                     kps[(size_t)b * CC + col] - EXP_SHIFT);
                    __builtin_nontemporal_store(p, &Out[(size_t)row * CC + col]);
                    racc[ni] += p;
                }
            }
        #pragma unroll
        for (int ni = 0; ni < 2; ++ni)
            atomicAdd(&ssum[(size_t)curb * CC + colb + ni * 16 + rl], racc[ni]);
        return;
    }

    if (MODE == 0) {
        // fast path: whole block in one segment
        int b = bfirst;
        float bb[2], kk[2];
        #pragma unroll
        for (int ni = 0; ni < 2; ++ni) {
            int col = colb + ni * 16 + rl;
            bb[ni] = bias[col];
            kk[ni] = kps[(size_t)b * CC + col];
        }
        v4f csum = {0.f, 0.f, 0.f, 0.f};
        #pragma unroll
        for (int mi = 0; mi < 2; ++mi) {
            #pragma unroll
            for (int r4 = 0; r4 < 4; ++r4)
                #pragma unroll
                for (int ni = 0; ni < 2; ++ni) {
                    float p = __expf((acc[mi][ni][r4] + bb[ni]) * kk[ni] - EXP_SHIFT);
                    lw[(kfl * 4 + r4) * EPW + ni * 16 + rl] = p;
                }
            __builtin_amdgcn_s_waitcnt(0);  // lgkm: wave-internal ds_write->ds_read
            #pragma unroll
            for (int j = 0; j < 2; ++j) {
                int rloc = j * 8 + r8;
                v4f pv = *(const v4f*)&lw[rloc * EPW + c8 * 4];
                __builtin_nontemporal_store(pv,
                    (v4f*)&Out[(size_t)(m0 + mi * 16 + rloc) * CC + colb + c8 * 4]);
                csum.x += pv.x; csum.y += pv.y; csum.z += pv.z; csum.w += pv.w;
            }
            if (mi == 0) __builtin_amdgcn_s_waitcnt(0);  // reads done before rewrite
        }
        // reduce col sums over the 8 r8 groups
        #pragma unroll
        for (int m = 8; m <= 32; m <<= 1) {
            csum.x += __shfl_xor(csum.x, m);
            csum.y += __shfl_xor(csum.y, m);
            csum.z += __shfl_xor(csum.z, m);
            csum.w += __shfl_xor(csum.w, m);
        }
        if (lane < 32) {
            int comp = (lane >> 3) & 3;
            int col = colb + c8 * 4 + comp;
            float vsum = (comp & 1) ? ((comp & 2) ? csum.w : csum.y)
                                    : ((comp & 2) ? csum.z : csum.x);
            atomicAdd(&ssum[(size_t)b * CC + col], vsum);
        }
    } else {
        float bb[2];
        #pragma unroll
        for (int ni = 0; ni < 2; ++ni) bb[ni] = bias[colb + ni * 16 + rl];
        #pragma unroll
        for (int mi = 0; mi < 2; ++mi) {
            #pragma unroll
            for (int r4 = 0; r4 < 4; ++r4)
                #pragma unroll
                for (int ni = 0; ni < 2; ++ni)
                    lw[(kfl * 4 + r4) * EPW + ni * 16 + rl] = acc[mi][ni][r4] + bb[ni];
            __builtin_amdgcn_s_waitcnt(0);
            #pragma unroll
            for (int j = 0; j < 2; ++j) {
                int rloc = j * 8 + r8;
                v4f pv = *(const v4f*)&lw[rloc * EPW + c8 * 4];
                __builtin_nontemporal_store(pv,
                    (v4f*)&Out[(size_t)(m0 + mi * 16 + rloc) * CC + colb + c8 * 4]);
            }
            if (mi == 0) __builtin_amdgcn_s_waitcnt(0);
        }
    }
}

// ---------------------------------------------------------------------------
// K_sv: SV[b,c] = vp[b,c] / ssum[b,c]
// ---------------------------------------------------------------------------
__global__ __launch_bounds__(256) void sv_kernel(
    const float* __restrict__ vp, const float* __restrict__ ssum,
    float* __restrict__ SV) {
    int i = blockIdx.x * 256 + threadIdx.x;
    SV[i] = vp[i] / ssum[i];
}

// ---------------------------------------------------------------------------
extern "C" void kernel_launch(void* const* d_in, const int* in_sizes, int n_in,
                              void* d_out, int out_size, void* d_ws, size_t ws_size,
                              hipStream_t stream) {
    const float* q  = (const float*)d_in[0];
    const float* k  = (const float*)d_in[1];
    const float* v  = (const float*)d_in[2];
    const int* batch = (const int*)d_in[3];
    const float* Wq = (const float*)d_in[4];
    const float* bq = (const float*)d_in[5];
    const float* Wk = (const float*)d_in[6];
    const float* bk = (const float*)d_in[7];
    const float* Wv = (const float*)d_in[8];
    const float* bv = (const float*)d_in[9];
    const float* Wo = (const float*)d_in[10];
    const float* bo = (const float*)d_in[11];
    float* out = (float*)d_out;

    char* wsp = (char*)d_ws;
    float* attn = (float*)wsp;  wsp += (size_t)N_PTS * CC * sizeof(float);       // 134 MB
    float* kps  = (float*)wsp;  wsp += (size_t)BSEG * CC * sizeof(float);
    float* vp   = (float*)wsp;  wsp += (size_t)BSEG * CC * sizeof(float);
    float* SVb  = (float*)wsp;  wsp += (size_t)BSEG * CC * sizeof(float);
    float* ssum = (float*)wsp;  wsp += (size_t)BSEG * CC * sizeof(float);
    short* W2q  = (short*)wsp;  wsp += (size_t)2 * 32 * 256 * 8 * sizeof(short); // 256 KB
    short* W2o  = (short*)wsp;  wsp += (size_t)2 * 32 * 256 * 8 * sizeof(short);

    kv_proj_kernel<<<BSEG, 256, 0, stream>>>(k, v, Wk, bk, Wv, bv, kps, vp, ssum);
    wsplit_kernel<<<64, 256, 0, stream>>>(Wq, Wo, W2q, W2o);

    gemm3_kernel<0><<<N_PTS / BM, 512, 0, stream>>>(
        q, W2q, bq, attn, batch, kps, nullptr, ssum);

    sv_kernel<<<BSEG, 256, 0, stream>>>(vp, ssum, SVb);

    gemm3_kernel<1><<<N_PTS / BM, 512, 0, stream>>>(
        attn, W2o, bo, out, batch, nullptr, SVb, nullptr);
}

// Round 9
// 183.262 us; speedup vs baseline: 1.6181x; 1.0887x over previous
//
#include <hip/hip_runtime.h>
#include <math.h>

#define N_PTS 131072
#define BSEG 64
#define CC 256
#define BM 64                    // rows per block; A tile fully LDS-resident
#define NSTEP 8                  // K-steps of 32
#define EXP_SHIFT 4.0f
#define PLANE2 32768             // bytes per LDS plane: 64 rows * 512B
#define EPW 36                   // epilogue bounce row stride (floats)

#define INV_SQRT_DH 0.17677669529663687f  // 1/sqrt(32)

typedef short v8s __attribute__((ext_vector_type(8)));
typedef float v4f __attribute__((ext_vector_type(4)));

__device__ __forceinline__ float bf2f(unsigned short h) {
    unsigned u = ((unsigned)h) << 16;
    return __builtin_bit_cast(float, u);
}

// f32 -> bf16 round-to-nearest-even
__device__ __forceinline__ unsigned short f2bf(float f) {
    unsigned u = __builtin_bit_cast(unsigned, f);
    u += 0x7fffu + ((u >> 16) & 1u);
    return (unsigned short)(u >> 16);
}

// split 8 fp32 -> hi/lo bf16 fragment pair (packed)
__device__ __forceinline__ void split8v(const float* x, v8s* hi, v8s* lo) {
    int h2[4], l2[4];
    #pragma unroll
    for (int i = 0; i < 4; ++i) {
        float a = x[2 * i], b = x[2 * i + 1];
        unsigned short ha = f2bf(a), hb = f2bf(b);
        float ra = a - bf2f(ha), rb = b - bf2f(hb);
        unsigned short la = f2bf(ra), lb = f2bf(rb);
        h2[i] = (int)(((unsigned)hb << 16) | ha);
        l2[i] = (int)(((unsigned)lb << 16) | la);
    }
    *hi = __builtin_bit_cast(v8s, make_int4(h2[0], h2[1], h2[2], h2[3]));
    *lo = __builtin_bit_cast(v8s, make_int4(l2[0], l2[1], l2[2], l2[3]));
}

__device__ __forceinline__ v8s as_v8s(int4 v) { return __builtin_bit_cast(v8s, v); }

// ---------------------------------------------------------------------------
// K1: kps = (k @ Wk^T + bk)/sqrt(DH) ; vp = v @ Wv^T + bv ; zero ssum
// ---------------------------------------------------------------------------
__global__ __launch_bounds__(256) void kv_proj_kernel(
    const float* __restrict__ k, const float* __restrict__ v,
    const float* __restrict__ Wk, const float* __restrict__ bk,
    const float* __restrict__ Wv, const float* __restrict__ bv,
    float* __restrict__ kps, float* __restrict__ vp, float* __restrict__ ssum) {
    int b = blockIdx.x;
    int c = threadIdx.x;
    const float4* krow  = (const float4*)(k + (size_t)b * CC);
    const float4* vrow  = (const float4*)(v + (size_t)b * CC);
    const float4* wkrow = (const float4*)(Wk + (size_t)c * CC);
    const float4* wvrow = (const float4*)(Wv + (size_t)c * CC);
    float accK = 0.f, accV = 0.f;
    #pragma unroll 8
    for (int i = 0; i < CC / 4; ++i) {
        float4 kk = krow[i], wk = wkrow[i];
        accK += kk.x * wk.x + kk.y * wk.y + kk.z * wk.z + kk.w * wk.w;
        float4 vv = vrow[i], wv = wvrow[i];
        accV += vv.x * wv.x + vv.y * wv.y + vv.z * wv.z + vv.w * wv.w;
    }
    kps[b * CC + c] = (accK + bk[c]) * INV_SQRT_DH;
    vp[b * CC + c] = accV + bv[c];
    ssum[b * CC + c] = 0.f;
}

// ---------------------------------------------------------------------------
// K1b: split Wq/Wo into hi/lo bf16 planes, layout W2[p][kf(32)][n(256)][8]
// ---------------------------------------------------------------------------
__global__ __launch_bounds__(256) void wsplit_kernel(
    const float* __restrict__ Wq, const float* __restrict__ Wo,
    short* __restrict__ W2q, short* __restrict__ W2o) {
    int bx = blockIdx.x;
    const float* W = (bx >= 32) ? Wo : Wq;
    short* W2 = (bx >= 32) ? W2o : W2q;
    int kf = bx & 31;
    int n = threadIdx.x;
    const float* src = W + (size_t)n * CC + kf * 8;
    float x[8];
    float4 x0 = *(const float4*)(src);
    float4 x1 = *(const float4*)(src + 4);
    x[0]=x0.x; x[1]=x0.y; x[2]=x0.z; x[3]=x0.w;
    x[4]=x1.x; x[5]=x1.y; x[6]=x1.z; x[7]=x1.w;
    v8s hi, lo;
    split8v(x, &hi, &lo);
    *(v8s*)&W2[((size_t)(0 * 32 + kf) * 256 + n) * 8] = hi;
    *(v8s*)&W2[((size_t)(1 * 32 + kf) * 256 + n) * 8] = lo;
}

// ---------------------------------------------------------------------------
// GEMM (bf16x3 MFMA): 512 thr / 8 waves. BM=64 x BN=256; each wave owns the
// full 64 rows x a 32-col strip: mi=4, ni=2 -> 24 MFMA per 4 B-loads per
// K-step. A tile (64 rows x K=256, hi+lo) staged in LDS once with an
// exactly-2-way swizzle; one barrier; 8 K-steps with 1-deep B prefetch; one
// barrier; LDS-bounce epilogue with coalesced nontemporal v4f stores.
//  MODE 0: A=q. p = exp((acc+bq[c])*kps[b,c]-4) -> attn; colsum -> ssum atomics.
//  MODE 1: A=p, staged transform x = p * SV[b,c]. Out: acc + bo[c].
// ---------------------------------------------------------------------------
template <int MODE>
__global__ __launch_bounds__(512, 4) void gemm3_kernel(
    const float* __restrict__ A, const short* __restrict__ W2,
    const float* __restrict__ bias, float* __restrict__ Out,
    const int* __restrict__ batch, const float* __restrict__ kps,
    const float* __restrict__ SV, float* __restrict__ ssum) {
    __shared__ char ldsb[2 * PLANE2];   // 64 KB

    const int tid = threadIdx.x;
    const int lane = tid & 63;
    const int wn = tid >> 6;        // 0..7: 32-col strip per wave
    const int kfl = lane >> 4;      // k-chunk 0..3 within a 32-k step
    const int rl = lane & 15;       // row (A) / col (B) within fragment
    const int m0 = blockIdx.x * BM;
    const int colb = wn * 32;

    // ---- stage A tile: fp32 -> split bf16 hi/lo, 2-way swizzled LDS ----
    #pragma unroll
    for (int i = 0; i < 4; ++i) {
        int j = i * 512 + tid;          // 0..2047
        int row = j >> 5;               // 0..63
        int ch = j & 31;                // 16B chunk (8 cols)
        const v4f* ap = (const v4f*)(A + (size_t)(m0 + row) * CC + ch * 8);
        v4f x0 = __builtin_nontemporal_load(ap);
        v4f x1 = __builtin_nontemporal_load(ap + 1);
        float x[8];
        x[0]=x0.x; x[1]=x0.y; x[2]=x0.z; x[3]=x0.w;
        x[4]=x1.x; x[5]=x1.y; x[6]=x1.z; x[7]=x1.w;
        if (MODE == 1) {
            int b = batch[m0 + row];
            const float4* sp = (const float4*)(SV + (size_t)b * CC + ch * 8);
            float4 s0 = sp[0];
            float4 s1 = sp[1];
            x[0] *= s0.x; x[1] *= s0.y; x[2] *= s0.z; x[3] *= s0.w;
            x[4] *= s1.x; x[5] *= s1.y; x[6] *= s1.z; x[7] *= s1.w;
        }
        v8s hi, lo;
        split8v(x, &hi, &lo);
        int h = ((row & 7) << 2) | ((row >> 3) & 1);   // h(row&15)
        int off = row * 512 + ((ch ^ h) << 4);
        *(v8s*)(ldsb + off) = hi;
        *(v8s*)(ldsb + PLANE2 + off) = lo;
    }

    v4f acc[4][2];
    #pragma unroll
    for (int i = 0; i < 4; ++i)
        #pragma unroll
        for (int j = 0; j < 2; ++j) acc[i][j] = (v4f){0.f, 0.f, 0.f, 0.f};

    // prefetch B for s=0 (independent of LDS)
    v8s bcur[2][2];
    #pragma unroll
    for (int p = 0; p < 2; ++p)
        #pragma unroll
        for (int ni = 0; ni < 2; ++ni)
            bcur[p][ni] = as_v8s(*(const int4*)(W2 +
                ((size_t)(p * 32 + kfl) * 256 + colb + ni * 16 + rl) * 8));

    const int hsw = ((rl & 7) << 2) | (rl >> 3);       // read-side swizzle

    __syncthreads();

    #pragma unroll
    for (int s = 0; s < NSTEP; ++s) {
        v8s bnx[2][2];
        if (s + 1 < NSTEP) {
            #pragma unroll
            for (int p = 0; p < 2; ++p)
                #pragma unroll
                for (int ni = 0; ni < 2; ++ni)
                    bnx[p][ni] = as_v8s(*(const int4*)(W2 +
                        ((size_t)(p * 32 + (s + 1) * 4 + kfl) * 256 + colb + ni * 16 + rl) * 8));
        }
        #pragma unroll
        for (int mi = 0; mi < 4; ++mi) {
            int abase = (mi * 16 + rl) * 512 + (((s * 4 + kfl) ^ hsw) << 4);
            v8s ah = *(const v8s*)(ldsb + abase);
            v8s al = *(const v8s*)(ldsb + PLANE2 + abase);
            #pragma unroll
            for (int ni = 0; ni < 2; ++ni) {
                acc[mi][ni] = __builtin_amdgcn_mfma_f32_16x16x32_bf16(
                    al, bcur[0][ni], acc[mi][ni], 0, 0, 0);   // lo*hi
                acc[mi][ni] = __builtin_amdgcn_mfma_f32_16x16x32_bf16(
                    ah, bcur[1][ni], acc[mi][ni], 0, 0, 0);   // hi*lo
                acc[mi][ni] = __builtin_amdgcn_mfma_f32_16x16x32_bf16(
                    ah, bcur[0][ni], acc[mi][ni], 0, 0, 0);   // hi*hi
            }
        }
        #pragma unroll
        for (int p = 0; p < 2; ++p)
            #pragma unroll
            for (int ni = 0; ni < 2; ++ni) bcur[p][ni] = bnx[p][ni];
    }

    __syncthreads();   // A-LDS dead; reuse for epilogue bounce

    int bfirst = batch[m0];
    int blast = batch[m0 + BM - 1];

    if (MODE == 0 && bfirst != blast) {
        // slow path: segment boundary inside block (rare; <64/2048 blocks)
        int curb = -1;
        float racc[2] = {0.f, 0.f};
        #pragma unroll
        for (int mi = 0; mi < 4; ++mi)
            #pragma unroll
            for (int r4 = 0; r4 < 4; ++r4) {
                int row = m0 + mi * 16 + kfl * 4 + r4;
                int b = batch[row];
                if (b != curb) {
                    if (curb >= 0) {
                        #pragma unroll
                        for (int ni = 0; ni < 2; ++ni) {
                            atomicAdd(&ssum[(size_t)curb * CC + colb + ni * 16 + rl], racc[ni]);
                            racc[ni] = 0.f;
                        }
                    }
                    curb = b;
                }
                #pragma unroll
                for (int ni = 0; ni < 2; ++ni) {
                    int col = colb + ni * 16 + rl;
                    float p = __expf((acc[mi][ni][r4] + bias[col]) *
                                     kps[(size_t)b * CC + col] - EXP_SHIFT);
                    Out[(size_t)row * CC + col] = p;
                    racc[ni] += p;
                }
            }
        #pragma unroll
        for (int ni = 0; ni < 2; ++ni)
            atomicAdd(&ssum[(size_t)curb * CC + colb + ni * 16 + rl], racc[ni]);
        return;
    }

    // per-wave bounce region: 32 rows x EPW floats (36 KB total)
    float* lw = (float*)ldsb + wn * (32 * EPW);
    const int c8 = lane & 7;        // col quad in strip
    const int r8 = lane >> 3;       // row-in-8 for readback

    if (MODE == 0) {
        // fast path: whole block in one segment
        int b = bfirst;
        float bb[2], kk[2];
        #pragma unroll
        for (int ni = 0; ni < 2; ++ni) {
            int col = colb + ni * 16 + rl;
            bb[ni] = bias[col];
            kk[ni] = kps[(size_t)b * CC + col];
        }
        v4f csum = {0.f, 0.f, 0.f, 0.f};
        #pragma unroll
        for (int ph = 0; ph < 2; ++ph) {
            #pragma unroll
            for (int q = 0; q < 2; ++q) {
                int mi = ph * 2 + q;
                #pragma unroll
                for (int r4 = 0; r4 < 4; ++r4)
                    #pragma unroll
                    for (int ni = 0; ni < 2; ++ni) {
                        float p = __expf((acc[mi][ni][r4] + bb[ni]) * kk[ni] - EXP_SHIFT);
                        lw[(q * 16 + kfl * 4 + r4) * EPW + ni * 16 + rl] = p;
                    }
            }
            asm volatile("s_waitcnt lgkmcnt(0)" ::: "memory");
            #pragma unroll
            for (int j = 0; j < 4; ++j) {
                int lr = j * 8 + r8;
                v4f pv = *(const v4f*)&lw[lr * EPW + c8 * 4];
                __builtin_nontemporal_store(pv,
                    (v4f*)&Out[(size_t)(m0 + ph * 32 + lr) * CC + colb + c8 * 4]);
                csum.x += pv.x; csum.y += pv.y; csum.z += pv.z; csum.w += pv.w;
            }
            asm volatile("s_waitcnt lgkmcnt(0)" ::: "memory");
        }
        // reduce col sums over the 8 r8 groups
        #pragma unroll
        for (int m = 8; m <= 32; m <<= 1) {
            csum.x += __shfl_xor(csum.x, m);
            csum.y += __shfl_xor(csum.y, m);
            csum.z += __shfl_xor(csum.z, m);
            csum.w += __shfl_xor(csum.w, m);
        }
        if (lane < 32) {
            int comp = lane >> 3;
            int col = colb + c8 * 4 + comp;
            float vsum = (comp & 1) ? ((comp & 2) ? csum.w : csum.y)
                                    : ((comp & 2) ? csum.z : csum.x);
            atomicAdd(&ssum[(size_t)b * CC + col], vsum);
        }
    } else {
        float bb[2];
        #pragma unroll
        for (int ni = 0; ni < 2; ++ni) bb[ni] = bias[colb + ni * 16 + rl];
        #pragma unroll
        for (int ph = 0; ph < 2; ++ph) {
            #pragma unroll
            for (int q = 0; q < 2; ++q) {
                int mi = ph * 2 + q;
                #pragma unroll
                for (int r4 = 0; r4 < 4; ++r4)
                    #pragma unroll
                    for (int ni = 0; ni < 2; ++ni)
                        lw[(q * 16 + kfl * 4 + r4) * EPW + ni * 16 + rl] =
                            acc[mi][ni][r4] + bb[ni];
            }
            asm volatile("s_waitcnt lgkmcnt(0)" ::: "memory");
            #pragma unroll
            for (int j = 0; j < 4; ++j) {
                int lr = j * 8 + r8;
                v4f pv = *(const v4f*)&lw[lr * EPW + c8 * 4];
                __builtin_nontemporal_store(pv,
                    (v4f*)&Out[(size_t)(m0 + ph * 32 + lr) * CC + colb + c8 * 4]);
            }
            asm volatile("s_waitcnt lgkmcnt(0)" ::: "memory");
        }
    }
}

// ---------------------------------------------------------------------------
// K_sv: SV[b,c] = vp[b,c] / ssum[b,c]
// ---------------------------------------------------------------------------
__global__ __launch_bounds__(256) void sv_kernel(
    const float* __restrict__ vp, const float* __restrict__ ssum,
    float* __restrict__ SV) {
    int i = blockIdx.x * 256 + threadIdx.x;
    SV[i] = vp[i] / ssum[i];
}

// ---------------------------------------------------------------------------
extern "C" void kernel_launch(void* const* d_in, const int* in_sizes, int n_in,
                              void* d_out, int out_size, void* d_ws, size_t ws_size,
                              hipStream_t stream) {
    const float* q  = (const float*)d_in[0];
    const float* k  = (const float*)d_in[1];
    const float* v  = (const float*)d_in[2];
    const int* batch = (const int*)d_in[3];
    const float* Wq = (const float*)d_in[4];
    const float* bq = (const float*)d_in[5];
    const float* Wk = (const float*)d_in[6];
    const float* bk = (const float*)d_in[7];
    const float* Wv = (const float*)d_in[8];
    const float* bv = (const float*)d_in[9];
    const float* Wo = (const float*)d_in[10];
    const float* bo = (const float*)d_in[11];
    float* out = (float*)d_out;

    char* wsp = (char*)d_ws;
    float* attn = (float*)wsp;  wsp += (size_t)N_PTS * CC * sizeof(float);       // 134 MB
    float* kps  = (float*)wsp;  wsp += (size_t)BSEG * CC * sizeof(float);
    float* vp   = (float*)wsp;  wsp += (size_t)BSEG * CC * sizeof(float);
    float* SVb  = (float*)wsp;  wsp += (size_t)BSEG * CC * sizeof(float);
    float* ssum = (float*)wsp;  wsp += (size_t)BSEG * CC * sizeof(float);
    short* W2q  = (short*)wsp;  wsp += (size_t)2 * 32 * 256 * 8 * sizeof(short); // 256 KB
    short* W2o  = (short*)wsp;  wsp += (size_t)2 * 32 * 256 * 8 * sizeof(short);

    kv_proj_kernel<<<BSEG, 256, 0, stream>>>(k, v, Wk, bk, Wv, bv, kps, vp, ssum);
    wsplit_kernel<<<64, 256, 0, stream>>>(Wq, Wo, W2q, W2o);

    gemm3_kernel<0><<<N_PTS / BM, 512, 0, stream>>>(
        q, W2q, bq, attn, batch, kps, nullptr, ssum);

    sv_kernel<<<BSEG, 256, 0, stream>>>(vp, ssum, SVb);

    gemm3_kernel<1><<<N_PTS / BM, 512, 0, stream>>>(
        attn, W2o, bo, out, batch, nullptr, SVb, nullptr);
}

// Round 10
// 163.647 us; speedup vs baseline: 1.8120x; 1.1199x over previous
//
#include <hip/hip_runtime.h>
#include <math.h>

#define N_PTS 131072
#define BSEG 64
#define CC 256
#define BM 64                    // rows per tile
#define TILES 4                  // tiles per persistent block
#define GRID 512                 // persistent blocks
#define EXP_SHIFT 4.0f

#define INV_SQRT_DH 0.17677669529663687f  // 1/sqrt(32)

typedef short v8s __attribute__((ext_vector_type(8)));
typedef float v4f __attribute__((ext_vector_type(4)));
typedef int   v4i __attribute__((ext_vector_type(4)));

__device__ __forceinline__ float bf2f(unsigned short h) {
    unsigned u = ((unsigned)h) << 16;
    return __builtin_bit_cast(float, u);
}

// f32 -> bf16 round-to-nearest-even
__device__ __forceinline__ unsigned short f2bf(float f) {
    unsigned u = __builtin_bit_cast(unsigned, f);
    u += 0x7fffu + ((u >> 16) & 1u);
    return (unsigned short)(u >> 16);
}

// split 8 fp32 -> hi/lo bf16 fragment pair (packed)
__device__ __forceinline__ void split8v(const float* x, v8s* hi, v8s* lo) {
    int h2[4], l2[4];
    #pragma unroll
    for (int i = 0; i < 4; ++i) {
        float a = x[2 * i], b = x[2 * i + 1];
        unsigned short ha = f2bf(a), hb = f2bf(b);
        float ra = a - bf2f(ha), rb = b - bf2f(hb);
        unsigned short la = f2bf(ra), lb = f2bf(rb);
        h2[i] = (int)(((unsigned)hb << 16) | ha);
        l2[i] = (int)(((unsigned)lb << 16) | la);
    }
    *hi = __builtin_bit_cast(v8s, make_int4(h2[0], h2[1], h2[2], h2[3]));
    *lo = __builtin_bit_cast(v8s, make_int4(l2[0], l2[1], l2[2], l2[3]));
}

// pack 8 fp32 -> 8 bf16 (RNE)
__device__ __forceinline__ v8s pack8(const float* x) {
    int h2[4];
    #pragma unroll
    for (int i = 0; i < 4; ++i)
        h2[i] = (int)(((unsigned)f2bf(x[2 * i + 1]) << 16) | f2bf(x[2 * i]));
    return __builtin_bit_cast(v8s, make_int4(h2[0], h2[1], h2[2], h2[3]));
}

__device__ __forceinline__ v8s as_v8s(int4 v) { return __builtin_bit_cast(v8s, v); }

// ---------------------------------------------------------------------------
// K1: kps = (k @ Wk^T + bk)/sqrt(DH) ; vp = v @ Wv^T + bv ; zero ssum
// ---------------------------------------------------------------------------
__global__ __launch_bounds__(256) void kv_proj_kernel(
    const float* __restrict__ k, const float* __restrict__ v,
    const float* __restrict__ Wk, const float* __restrict__ bk,
    const float* __restrict__ Wv, const float* __restrict__ bv,
    float* __restrict__ kps, float* __restrict__ vp, float* __restrict__ ssum) {
    int b = blockIdx.x;
    int c = threadIdx.x;
    const float4* krow  = (const float4*)(k + (size_t)b * CC);
    const float4* vrow  = (const float4*)(v + (size_t)b * CC);
    const float4* wkrow = (const float4*)(Wk + (size_t)c * CC);
    const float4* wvrow = (const float4*)(Wv + (size_t)c * CC);
    float accK = 0.f, accV = 0.f;
    #pragma unroll 8
    for (int i = 0; i < CC / 4; ++i) {
        float4 kk = krow[i], wk = wkrow[i];
        accK += kk.x * wk.x + kk.y * wk.y + kk.z * wk.z + kk.w * wk.w;
        float4 vv = vrow[i], wv = wvrow[i];
        accV += vv.x * wv.x + vv.y * wv.y + vv.z * wv.z + vv.w * wv.w;
    }
    kps[b * CC + c] = (accK + bk[c]) * INV_SQRT_DH;
    vp[b * CC + c] = accV + bv[c];
    ssum[b * CC + c] = 0.f;
}

// ---------------------------------------------------------------------------
// K1b: split Wq/Wo into hi/lo bf16 planes, layout W2[p][kf(32)][n(256)][8]
// ---------------------------------------------------------------------------
__global__ __launch_bounds__(256) void wsplit_kernel(
    const float* __restrict__ Wq, const float* __restrict__ Wo,
    short* __restrict__ W2q, short* __restrict__ W2o) {
    int bx = blockIdx.x;
    const float* W = (bx >= 32) ? Wo : Wq;
    short* W2 = (bx >= 32) ? W2o : W2q;
    int kf = bx & 31;
    int n = threadIdx.x;
    const float* src = W + (size_t)n * CC + kf * 8;
    float x[8];
    float4 x0 = *(const float4*)(src);
    float4 x1 = *(const float4*)(src + 4);
    x[0]=x0.x; x[1]=x0.y; x[2]=x0.z; x[3]=x0.w;
    x[4]=x1.x; x[5]=x1.y; x[6]=x1.z; x[7]=x1.w;
    v8s hi, lo;
    split8v(x, &hi, &lo);
    *(v8s*)&W2[((size_t)(0 * 32 + kf) * 256 + n) * 8] = hi;
    *(v8s*)&W2[((size_t)(1 * 32 + kf) * 256 + n) * 8] = lo;
}

// ---------------------------------------------------------------------------
// Persistent GEMM (bf16x3 / bf16x2 MFMA). 512 blocks x 512 thr (8 waves);
// each wave owns a 32-col strip; its B strip (hi+lo, full K) lives in 128
// VGPRs loaded ONCE and reused across 4 tiles -> K-loop is pure ds_read+MFMA.
//  MODE 0: A=q fp32 (split hi/lo in LDS, 24 MFMA/step).
//          Epilogue: p = exp((acc+bq)*kps[b,c]-4); write bf16 p; ssum atomics.
//  MODE 1: A=p bf16 (single LDS plane, staged transform x = bf16(p*SV[b,c]),
//          16 MFMA/step). Epilogue: out = acc + bo (f32).
// ---------------------------------------------------------------------------
template <int MODE>
__global__ __launch_bounds__(512, 2) void gemm3_kernel(
    const void* __restrict__ Ain, const short* __restrict__ W2,
    const float* __restrict__ bias, void* __restrict__ Outv,
    const int* __restrict__ batch, const float* __restrict__ kps,
    const float* __restrict__ SV, float* __restrict__ ssum) {

    constexpr int PL = 32768;          // bytes per A plane (64 rows * 512B)
    __shared__ char ldsb[(MODE == 0) ? 2 * PL : PL];

    const int tid = threadIdx.x;
    const int lane = tid & 63;
    const int wn = tid >> 6;           // 0..7: 32-col strip
    const int kfl = lane >> 4;         // k-chunk 0..3
    const int rl = lane & 15;          // row (A) / col (B) in fragment
    const int colb = wn * 32;
    const int hsw = ((rl & 7) << 2) | (rl >> 3);

    // ---- B strip resident in VGPRs: [plane][step][ni], 32 x v8s ----
    v8s Bv[2][8][2];
    #pragma unroll
    for (int p = 0; p < 2; ++p)
        #pragma unroll
        for (int s = 0; s < 8; ++s)
            #pragma unroll
            for (int ni = 0; ni < 2; ++ni)
                Bv[p][s][ni] = as_v8s(*(const int4*)(W2 +
                    ((size_t)(p * 32 + s * 4 + kfl) * 256 + colb + ni * 16 + rl) * 8));

    const float bb0 = bias[colb + rl];
    const float bb1 = bias[colb + 16 + rl];

    for (int t = 0; t < TILES; ++t) {
        const int m0 = (blockIdx.x * TILES + t) * BM;
        if (t) __syncthreads();   // prev epilogue done before LDS reuse

        // ---- stage A tile (swizzled) ----
        #pragma unroll
        for (int i = 0; i < 4; ++i) {
            int j = i * 512 + tid;          // 0..2047
            int row = j >> 5;               // 0..63
            int ch = j & 31;                // 16B chunk
            int h = ((row & 7) << 2) | ((row >> 3) & 1);
            int off = row * 512 + ((ch ^ h) << 4);
            if (MODE == 0) {
                const v4f* ap = (const v4f*)((const float*)Ain +
                    (size_t)(m0 + row) * CC + ch * 8);
                v4f x0 = __builtin_nontemporal_load(ap);
                v4f x1 = __builtin_nontemporal_load(ap + 1);
                float x[8] = {x0.x, x0.y, x0.z, x0.w, x1.x, x1.y, x1.z, x1.w};
                v8s hi, lo;
                split8v(x, &hi, &lo);
                *(v8s*)(ldsb + off) = hi;
                *(v8s*)(ldsb + PL + off) = lo;
            } else {
                const v4i* ap = (const v4i*)((const unsigned short*)Ain +
                    (size_t)(m0 + row) * CC + ch * 8);
                v4i raw = __builtin_nontemporal_load(ap);
                v8s pv = __builtin_bit_cast(v8s, raw);
                int b = batch[m0 + row];
                const float* svp = SV + (size_t)b * CC + ch * 8;
                v4f s0 = *(const v4f*)svp;
                v4f s1 = *(const v4f*)(svp + 4);
                float x[8];
                #pragma unroll
                for (int e = 0; e < 4; ++e) {
                    x[e]     = bf2f((unsigned short)pv[e]) * s0[e];
                    x[4 + e] = bf2f((unsigned short)pv[4 + e]) * s1[e];
                }
                *(v8s*)(ldsb + off) = pack8(x);
            }
        }
        __syncthreads();

        // ---- K-loop: pure LDS + MFMA ----
        v4f acc[4][2];
        #pragma unroll
        for (int i = 0; i < 4; ++i)
            #pragma unroll
            for (int j = 0; j < 2; ++j) acc[i][j] = (v4f){0.f, 0.f, 0.f, 0.f};

        #pragma unroll
        for (int s = 0; s < 8; ++s) {
            #pragma unroll
            for (int mi = 0; mi < 4; ++mi) {
                int abase = (mi * 16 + rl) * 512 + (((s * 4 + kfl) ^ hsw) << 4);
                if (MODE == 0) {
                    v8s ah = *(const v8s*)(ldsb + abase);
                    v8s al = *(const v8s*)(ldsb + PL + abase);
                    #pragma unroll
                    for (int ni = 0; ni < 2; ++ni) {
                        acc[mi][ni] = __builtin_amdgcn_mfma_f32_16x16x32_bf16(
                            al, Bv[0][s][ni], acc[mi][ni], 0, 0, 0);   // lo*hi
                        acc[mi][ni] = __builtin_amdgcn_mfma_f32_16x16x32_bf16(
                            ah, Bv[1][s][ni], acc[mi][ni], 0, 0, 0);   // hi*lo
                        acc[mi][ni] = __builtin_amdgcn_mfma_f32_16x16x32_bf16(
                            ah, Bv[0][s][ni], acc[mi][ni], 0, 0, 0);   // hi*hi
                    }
                } else {
                    v8s a = *(const v8s*)(ldsb + abase);
                    #pragma unroll
                    for (int ni = 0; ni < 2; ++ni) {
                        acc[mi][ni] = __builtin_amdgcn_mfma_f32_16x16x32_bf16(
                            a, Bv[1][s][ni], acc[mi][ni], 0, 0, 0);    // a*lo
                        acc[mi][ni] = __builtin_amdgcn_mfma_f32_16x16x32_bf16(
                            a, Bv[0][s][ni], acc[mi][ni], 0, 0, 0);    // a*hi
                    }
                }
            }
        }
        __syncthreads();   // all A-reads done; LDS reusable for bounce

        // ---- epilogue ----
        if (MODE == 0) {
            unsigned short* Ou = (unsigned short*)Outv;
            int bfirst = batch[m0];
            int blast = batch[m0 + BM - 1];
            if (bfirst != blast) {
                // slow path: segment boundary inside tile (rare)
                int curb = -1;
                float r0 = 0.f, r1 = 0.f;
                #pragma unroll
                for (int mi = 0; mi < 4; ++mi)
                    #pragma unroll
                    for (int r4 = 0; r4 < 4; ++r4) {
                        int row = m0 + mi * 16 + kfl * 4 + r4;
                        int b = batch[row];
                        if (b != curb) {
                            if (curb >= 0) {
                                atomicAdd(&ssum[(size_t)curb * CC + colb + rl], r0);
                                atomicAdd(&ssum[(size_t)curb * CC + colb + 16 + rl], r1);
                                r0 = r1 = 0.f;
                            }
                            curb = b;
                        }
                        float k0 = kps[(size_t)b * CC + colb + rl];
                        float k1 = kps[(size_t)b * CC + colb + 16 + rl];
                        float p0 = __expf((acc[mi][0][r4] + bb0) * k0 - EXP_SHIFT);
                        float p1 = __expf((acc[mi][1][r4] + bb1) * k1 - EXP_SHIFT);
                        Ou[(size_t)row * CC + colb + rl] = f2bf(p0);
                        Ou[(size_t)row * CC + colb + 16 + rl] = f2bf(p1);
                        r0 += p0; r1 += p1;
                    }
                atomicAdd(&ssum[(size_t)curb * CC + colb + rl], r0);
                atomicAdd(&ssum[(size_t)curb * CC + colb + 16 + rl], r1);
            } else {
                int b = bfirst;
                float k0 = kps[(size_t)b * CC + colb + rl];
                float k1 = kps[(size_t)b * CC + colb + 16 + rl];
                float cs0 = 0.f, cs1 = 0.f;
                unsigned short* lwu = (unsigned short*)ldsb + wn * (16 * 40);
                #pragma unroll
                for (int mi = 0; mi < 4; ++mi) {
                    #pragma unroll
                    for (int r4 = 0; r4 < 4; ++r4) {
                        float p0 = __expf((acc[mi][0][r4] + bb0) * k0 - EXP_SHIFT);
                        float p1 = __expf((acc[mi][1][r4] + bb1) * k1 - EXP_SHIFT);
                        cs0 += p0; cs1 += p1;
                        lwu[(kfl * 4 + r4) * 40 + rl] = f2bf(p0);
                        lwu[(kfl * 4 + r4) * 40 + 16 + rl] = f2bf(p1);
                    }
                    asm volatile("s_waitcnt lgkmcnt(0)" ::: "memory");
                    int row16 = lane >> 2, chunk = lane & 3;
                    v4i pv = *(const v4i*)&lwu[row16 * 40 + chunk * 8];
                    __builtin_nontemporal_store(pv,
                        (v4i*)&Ou[(size_t)(m0 + mi * 16 + row16) * CC + colb + chunk * 8]);
                    asm volatile("s_waitcnt lgkmcnt(0)" ::: "memory");
                }
                cs0 += __shfl_xor(cs0, 16); cs0 += __shfl_xor(cs0, 32);
                cs1 += __shfl_xor(cs1, 16); cs1 += __shfl_xor(cs1, 32);
                if (kfl == 0) {
                    atomicAdd(&ssum[(size_t)b * CC + colb + rl], cs0);
                    atomicAdd(&ssum[(size_t)b * CC + colb + 16 + rl], cs1);
                }
            }
        } else {
            float* Of = (float*)Outv;
            float* lwf = (float*)ldsb + wn * (16 * 36);
            #pragma unroll
            for (int mi = 0; mi < 4; ++mi) {
                #pragma unroll
                for (int r4 = 0; r4 < 4; ++r4) {
                    lwf[(kfl * 4 + r4) * 36 + rl] = acc[mi][0][r4] + bb0;
                    lwf[(kfl * 4 + r4) * 36 + 16 + rl] = acc[mi][1][r4] + bb1;
                }
                asm volatile("s_waitcnt lgkmcnt(0)" ::: "memory");
                #pragma unroll
                for (int j = 0; j < 2; ++j) {
                    int row16 = j * 8 + (lane >> 3);
                    int chunk = lane & 7;
                    v4f pv = *(const v4f*)&lwf[row16 * 36 + chunk * 4];
                    __builtin_nontemporal_store(pv,
                        (v4f*)&Of[(size_t)(m0 + mi * 16 + row16) * CC + colb + chunk * 4]);
                }
                asm volatile("s_waitcnt lgkmcnt(0)" ::: "memory");
            }
        }
    }
}

// ---------------------------------------------------------------------------
// K_sv: SV[b,c] = vp[b,c] / ssum[b,c]
// ---------------------------------------------------------------------------
__global__ __launch_bounds__(256) void sv_kernel(
    const float* __restrict__ vp, const float* __restrict__ ssum,
    float* __restrict__ SV) {
    int i = blockIdx.x * 256 + threadIdx.x;
    SV[i] = vp[i] / ssum[i];
}

// ---------------------------------------------------------------------------
extern "C" void kernel_launch(void* const* d_in, const int* in_sizes, int n_in,
                              void* d_out, int out_size, void* d_ws, size_t ws_size,
                              hipStream_t stream) {
    const float* q  = (const float*)d_in[0];
    const float* k  = (const float*)d_in[1];
    const float* v  = (const float*)d_in[2];
    const int* batch = (const int*)d_in[3];
    const float* Wq = (const float*)d_in[4];
    const float* bq = (const float*)d_in[5];
    const float* Wk = (const float*)d_in[6];
    const float* bk = (const float*)d_in[7];
    const float* Wv = (const float*)d_in[8];
    const float* bv = (const float*)d_in[9];
    const float* Wo = (const float*)d_in[10];
    const float* bo = (const float*)d_in[11];
    float* out = (float*)d_out;

    char* wsp = (char*)d_ws;
    unsigned short* attn = (unsigned short*)wsp;
    wsp += (size_t)N_PTS * CC * sizeof(unsigned short);                          // 67 MB
    float* kps  = (float*)wsp;  wsp += (size_t)BSEG * CC * sizeof(float);
    float* vp   = (float*)wsp;  wsp += (size_t)BSEG * CC * sizeof(float);
    float* SVb  = (float*)wsp;  wsp += (size_t)BSEG * CC * sizeof(float);
    float* ssum = (float*)wsp;  wsp += (size_t)BSEG * CC * sizeof(float);
    short* W2q  = (short*)wsp;  wsp += (size_t)2 * 32 * 256 * 8 * sizeof(short); // 256 KB
    short* W2o  = (short*)wsp;  wsp += (size_t)2 * 32 * 256 * 8 * sizeof(short);

    kv_proj_kernel<<<BSEG, 256, 0, stream>>>(k, v, Wk, bk, Wv, bv, kps, vp, ssum);
    wsplit_kernel<<<64, 256, 0, stream>>>(Wq, Wo, W2q, W2o);

    gemm3_kernel<0><<<GRID, 512, 0, stream>>>(
        (const void*)q, W2q, bq, (void*)attn, batch, kps, nullptr, ssum);

    sv_kernel<<<BSEG, 256, 0, stream>>>(vp, ssum, SVb);

    gemm3_kernel<1><<<GRID, 512, 0, stream>>>(
        (const void*)attn, W2o, bo, (void*)out, batch, nullptr, SVb, nullptr);
}